// Round 1
// baseline (148.985 us; speedup 1.0000x reference)
//
#include <hip/hip_runtime.h>

// DescriptorMatcher match_snn: dm = ||a-b||, top-2 per row, ratio test @ 0.8.
// Strategy: bf16 MFMA GEMM (D1 @ D2^T) fused with on-the-fly per-row top-2;
// two-phase reduction over column chunks; all outputs written as float32.

typedef __bf16 bf16x8 __attribute__((ext_vector_type(8)));
typedef __bf16 bf16x2 __attribute__((ext_vector_type(2)));
typedef float f32x4 __attribute__((ext_vector_type(4)));

#define NB1 8192
#define NB2 8192
#define DK 128
#define NCHUNK 16
#define CHUNK (NB2 / NCHUNK) /* 512 cols per chunk */
#define BM 128               /* rows per block (4 waves x 32 rows) */

// --- convert fp32 -> bf16 row-major, and compute per-row squared norms -----
__global__ __launch_bounds__(256) void conv_norm_kernel(const float* __restrict__ src,
                                                        __bf16* __restrict__ dst,
                                                        float* __restrict__ nrm) {
    const int row  = blockIdx.x * 4 + (threadIdx.x >> 6); // one wave per row
    const int lane = threadIdx.x & 63;
    const size_t off = (size_t)row * DK + lane * 2;
    const float2 v = *reinterpret_cast<const float2*>(src + off);
    float s = v.x * v.x + v.y * v.y;
    bf16x2 bp;
    bp[0] = (__bf16)v.x;
    bp[1] = (__bf16)v.y;
    *reinterpret_cast<bf16x2*>(dst + off) = bp;
#pragma unroll
    for (int d = 1; d < 64; d <<= 1) s += __shfl_xor(s, d);
    if (lane == 0) nrm[row] = s;
}

// --- main: per (128-row block, 512-col chunk): MFMA GEMM + running top-2 ---
// m = n2[j] - 2*dot(a_i,b_j)   (n1[i] is a per-row constant, added in phase 2)
__global__ __launch_bounds__(256) void snn_main_kernel(const __bf16* __restrict__ d1b,
                                                       const __bf16* __restrict__ d2b,
                                                       const float* __restrict__ n2,
                                                       float* __restrict__ pmin1,
                                                       float* __restrict__ pmin2,
                                                       int* __restrict__ pidx) {
    const int lane    = threadIdx.x & 63;
    const int wid     = threadIdx.x >> 6;
    const int rowbase = blockIdx.x * BM + wid * 32; // wave owns 32 rows (2 row-tiles)
    const int colbase = blockIdx.y * CHUNK;
    const int lrow    = lane & 15;
    const int lk      = (lane >> 4) * 8;

    // A fragments: row = lane&15, k = (lane>>4)*8 + b  (8 contiguous bf16)
    bf16x8 afrag[2][4];
#pragma unroll
    for (int r = 0; r < 2; ++r)
#pragma unroll
        for (int kk = 0; kk < 4; ++kk)
            afrag[r][kk] = *reinterpret_cast<const bf16x8*>(
                d1b + (size_t)(rowbase + r * 16 + lrow) * DK + kk * 32 + lk);

    float mn1[8], mn2[8];
    int id1[8];
#pragma unroll
    for (int s = 0; s < 8; ++s) { mn1[s] = 1e30f; mn2[s] = 1e30f; id1[s] = 0; }

    const __bf16* bbase = d2b + (size_t)(colbase + lrow) * DK + lk;
    const float* n2p = n2 + colbase + lrow;

    for (int jt = 0; jt < CHUNK / 16; ++jt) {
        const __bf16* bp = bbase + (size_t)jt * 16 * DK;
        bf16x8 bfrag[4];
#pragma unroll
        for (int kk = 0; kk < 4; ++kk)
            bfrag[kk] = *reinterpret_cast<const bf16x8*>(bp + kk * 32);
        const float n2c = n2p[jt * 16];
        const int col = colbase + jt * 16 + lrow;
#pragma unroll
        for (int r = 0; r < 2; ++r) {
            f32x4 acc = {0.f, 0.f, 0.f, 0.f};
#pragma unroll
            for (int kk = 0; kk < 4; ++kk)
                acc = __builtin_amdgcn_mfma_f32_16x16x32_bf16(afrag[r][kk], bfrag[kk], acc, 0, 0, 0);
            // C/D layout (HW-verified): col = lane&15, row = (lane>>4)*4 + e
#pragma unroll
            for (int e = 0; e < 4; ++e) {
                const float m = fmaf(-2.0f, acc[e], n2c);
                const int s = r * 4 + e;
                if (m < mn2[s]) { // rarely taken after warm-up
                    if (m < mn1[s]) { mn2[s] = mn1[s]; mn1[s] = m; id1[s] = col; }
                    else mn2[s] = m;
                }
            }
        }
    }

    // cross-lane top-2 merge within each 16-lane group (same rows, 16 cols)
#pragma unroll
    for (int s = 0; s < 8; ++s) {
        float a1 = mn1[s], a2 = mn2[s];
        int ai = id1[s];
#pragma unroll
        for (int d = 1; d <= 8; d <<= 1) {
            const float o1 = __shfl_xor(a1, d);
            const float o2 = __shfl_xor(a2, d);
            const int oi = __shfl_xor(ai, d);
            const bool aw = (a1 < o1) || (a1 == o1 && ai < oi); // ties: lower col
            const float w2 = aw ? o1 : a1;
            a1 = aw ? a1 : o1;
            ai = aw ? ai : oi;
            a2 = fminf(w2, fminf(a2, o2));
        }
        if (lrow == 0) {
            const int row = rowbase + (s >> 2) * 16 + (lane >> 4) * 4 + (s & 3);
            const size_t off = (size_t)blockIdx.y * NB1 + row;
            pmin1[off] = a1;
            pmin2[off] = a2;
            pidx[off] = ai;
        }
    }
}

// --- phase 2: merge chunk partials, ratio test, write outputs --------------
__global__ __launch_bounds__(256) void snn_reduce_kernel(const float* __restrict__ pmin1,
                                                         const float* __restrict__ pmin2,
                                                         const int* __restrict__ pidx,
                                                         const float* __restrict__ n1,
                                                         float* __restrict__ out) {
    const int i = blockIdx.x * 256 + threadIdx.x;
    float m1 = 1e30f, m2 = 1e30f;
    int idx = 0;
#pragma unroll
    for (int c = 0; c < NCHUNK; ++c) { // ascending chunk => ties pick lower col
        const float c1 = pmin1[(size_t)c * NB1 + i];
        const float c2 = pmin2[(size_t)c * NB1 + i];
        const int ci = pidx[(size_t)c * NB1 + i];
        if (c1 < m1) { m2 = fminf(m1, c2); m1 = c1; idx = ci; }
        else m2 = fminf(m2, c1);
    }
    const float nn = n1[i];
    const float d1 = sqrtf(fmaxf(nn + m1, 0.f));
    const float d2 = sqrtf(fmaxf(nn + m2, 0.f));
    const float ratio = d1 / d2;
    const bool mask = (ratio <= 0.8f); // NaN (d2==0) -> false, matches jnp
    out[i] = mask ? ratio : 0.0f;                       // match_dists (8192,1)
    out[NB1 + 2 * i] = mask ? (float)i : -1.0f;         // matches_idxs[:,0]
    out[NB1 + 2 * i + 1] = mask ? (float)idx : -1.0f;   // matches_idxs[:,1]
    out[3 * NB1 + i] = mask ? 1.0f : 0.0f;              // mask
}

extern "C" void kernel_launch(void* const* d_in, const int* in_sizes, int n_in,
                              void* d_out, int out_size, void* d_ws, size_t ws_size,
                              hipStream_t stream) {
    const float* desc1 = (const float*)d_in[0];
    const float* desc2 = (const float*)d_in[1];
    float* out = (float*)d_out;
    char* ws = (char*)d_ws;

    __bf16* d1b = (__bf16*)ws;                                  // 2 MB
    __bf16* d2b = (__bf16*)(ws + (size_t)2 * 1024 * 1024);      // 2 MB
    float* n1 = (float*)(ws + (size_t)4 * 1024 * 1024);         // 32 KB
    float* n2 = (float*)(ws + (size_t)4 * 1024 * 1024 + 32768); // 32 KB
    float* pmin1 = (float*)(ws + (size_t)4 * 1024 * 1024 + 65536);
    float* pmin2 = pmin1 + (size_t)NCHUNK * NB1;
    int* pidx = (int*)(pmin2 + (size_t)NCHUNK * NB1);

    conv_norm_kernel<<<NB1 / 4, 256, 0, stream>>>(desc1, d1b, n1);
    conv_norm_kernel<<<NB2 / 4, 256, 0, stream>>>(desc2, d2b, n2);
    snn_main_kernel<<<dim3(NB1 / BM, NCHUNK), 256, 0, stream>>>(d1b, d2b, n2, pmin1, pmin2, pidx);
    snn_reduce_kernel<<<NB1 / 256, 256, 0, stream>>>(pmin1, pmin2, pidx, n1, out);
}

// Round 10
// 101.938 us; speedup vs baseline: 1.4615x; 1.4615x over previous
//
#include <hip/hip_runtime.h>

// DescriptorMatcher match_snn — R2 (resubmit x8; broker timeouts, kernel never ran).
// bf16 MFMA GEMM fused with branchless packed-int top-2:
//   A pre-scaled by -2, acc initialized to n2+C  =>  acc exits K-loop = m' = n2+C-2*dot > 0
//   packed u = (bits(m') & 0xFFFFE000) | col ; top-2 via u32 min/max (3 ops), index embedded.

typedef __bf16 bf16x8 __attribute__((ext_vector_type(8)));
typedef __bf16 bf16x2 __attribute__((ext_vector_type(2)));
typedef float f32x4 __attribute__((ext_vector_type(4)));

#define NB 8192
#define DK 128
#define NCHUNK 16
#define CHUNK (NB / NCHUNK)   /* 512 cols per chunk */
#define ROWS_PER_WAVE 64      /* 4 row-tiles of 16 */
#define BM 256                /* 4 waves per block */
#define COFF 512.0f           /* positivity offset for packed ordering */
#define VMASK 0xFFFFE000u     /* keep sign+exp+10 mantissa bits; low 13 = col */

// --- fused convert: desc1 -> -2*bf16, n1 raw ; desc2 -> bf16, n2+COFF ------
__global__ __launch_bounds__(256) void conv_norm_kernel(const float* __restrict__ desc1,
                                                        const float* __restrict__ desc2,
                                                        __bf16* __restrict__ d1b,
                                                        __bf16* __restrict__ d2b,
                                                        float* __restrict__ n1,
                                                        float* __restrict__ n2pc) {
    const int idx  = blockIdx.x * 4 + (threadIdx.x >> 6); // one wave per row
    const int lane = threadIdx.x & 63;
    const bool is2 = idx >= NB;
    const int row  = is2 ? idx - NB : idx;
    const float* src = is2 ? desc2 : desc1;
    const size_t off = (size_t)row * DK + lane * 2;
    const float2 v = *reinterpret_cast<const float2*>(src + off);
    float s = v.x * v.x + v.y * v.y;
    const float sc = is2 ? 1.0f : -2.0f;
    bf16x2 bp;
    bp[0] = (__bf16)(v.x * sc);
    bp[1] = (__bf16)(v.y * sc);
    *reinterpret_cast<bf16x2*>((is2 ? d2b : d1b) + off) = bp;
#pragma unroll
    for (int d = 1; d < 64; d <<= 1) s += __shfl_xor(s, d);
    if (lane == 0) {
        if (is2) n2pc[row] = s + COFF;
        else     n1[row] = s;
    }
}

// --- main: wave owns 64 rows x 512-col chunk; fused GEMM + packed top-2 ----
__global__ __launch_bounds__(256) void snn_main_kernel(const __bf16* __restrict__ d1b,
                                                       const __bf16* __restrict__ d2b,
                                                       const float* __restrict__ n2pc,
                                                       unsigned* __restrict__ pmin1,
                                                       unsigned* __restrict__ pmin2) {
    const int lane    = threadIdx.x & 63;
    const int wid     = threadIdx.x >> 6;
    const int rowbase = blockIdx.x * BM + wid * ROWS_PER_WAVE;
    const int colbase = blockIdx.y * CHUNK;
    const int lrow    = lane & 15;
    const int lk      = (lane >> 4) * 8;

    // A fragments (row = lane&15, k = (lane>>4)*8 + b) — A is pre-scaled by -2
    bf16x8 afrag[4][4];
#pragma unroll
    for (int rt = 0; rt < 4; ++rt)
#pragma unroll
        for (int kk = 0; kk < 4; ++kk)
            afrag[rt][kk] = *reinterpret_cast<const bf16x8*>(
                d1b + (size_t)(rowbase + rt * 16 + lrow) * DK + kk * 32 + lk);

    unsigned p1[16], p2[16];
#pragma unroll
    for (int s = 0; s < 16; ++s) { p1[s] = 0xFFFFFFFFu; p2[s] = 0xFFFFFFFFu; }

    const __bf16* bbase = d2b + (size_t)(colbase + lrow) * DK + lk;
    const float* n2p = n2pc + colbase + lrow;
    const unsigned colv = colbase + lrow;

    for (int jt = 0; jt < CHUNK / 16; ++jt) {
        const __bf16* bp = bbase + (size_t)jt * 16 * DK;
        bf16x8 bfrag[4];
#pragma unroll
        for (int kk = 0; kk < 4; ++kk)
            bfrag[kk] = *reinterpret_cast<const bf16x8*>(bp + kk * 32);
        const float n2c = n2p[jt * 16];      // per-lane col constant (col = lane&15)
        const unsigned col = colv + jt * 16;
#pragma unroll
        for (int rt = 0; rt < 4; ++rt) {
            f32x4 acc = {n2c, n2c, n2c, n2c}; // acc exits loop = n2 + C - 2*dot
#pragma unroll
            for (int kk = 0; kk < 4; ++kk)
                acc = __builtin_amdgcn_mfma_f32_16x16x32_bf16(afrag[rt][kk], bfrag[kk], acc, 0, 0, 0);
            // C/D layout: col = lane&15, row = (lane>>4)*4 + e
#pragma unroll
            for (int e = 0; e < 4; ++e) {
                const unsigned u = (__builtin_bit_cast(unsigned, acc[e]) & VMASK) | col;
                const int s = rt * 4 + e;
                const unsigned t = max(p1[s], u);
                p1[s] = min(p1[s], u);
                p2[s] = min(p2[s], t);
            }
        }
    }

    // cross-lane top-2 merge within each 16-lane group (same rows, diff cols)
#pragma unroll
    for (int s = 0; s < 16; ++s) {
        unsigned a1 = p1[s], a2 = p2[s];
#pragma unroll
        for (int d = 1; d <= 8; d <<= 1) {
            const unsigned o1 = __shfl_xor(a1, d);
            const unsigned o2 = __shfl_xor(a2, d);
            const unsigned t = max(a1, o1);
            a1 = min(a1, o1);
            a2 = min(min(a2, o2), t);
        }
        if (lrow == 0) {
            const int row = rowbase + (s >> 2) * 16 + (lane >> 4) * 4 + (s & 3);
            const size_t off = (size_t)blockIdx.y * NB + row;
            pmin1[off] = a1;
            pmin2[off] = a2;
        }
    }
}

// --- phase 2: merge chunk partials (packed), ratio test, write outputs -----
__global__ __launch_bounds__(256) void snn_reduce_kernel(const unsigned* __restrict__ pmin1,
                                                         const unsigned* __restrict__ pmin2,
                                                         const float* __restrict__ n1,
                                                         float* __restrict__ out) {
    const int i = blockIdx.x * 256 + threadIdx.x;
    unsigned a1 = 0xFFFFFFFFu, a2 = 0xFFFFFFFFu;
#pragma unroll
    for (int c = 0; c < NCHUNK; ++c) {
        const unsigned c1 = pmin1[(size_t)c * NB + i];
        const unsigned c2 = pmin2[(size_t)c * NB + i];
        const unsigned t = max(a1, c1);
        a1 = min(a1, c1);
        a2 = min(min(a2, c2), t);
    }
    const float v1 = __builtin_bit_cast(float, a1 & VMASK) - COFF; // n2 - 2*dot
    const float v2 = __builtin_bit_cast(float, a2 & VMASK) - COFF;
    const int idx = (int)(a1 & 0x1FFFu);
    const float nn = n1[i];
    const float d1 = sqrtf(fmaxf(nn + v1, 0.f));
    const float d2 = sqrtf(fmaxf(nn + v2, 0.f));
    const float ratio = d1 / d2;
    const bool mask = (ratio <= 0.8f); // NaN -> false, matches jnp
    out[i] = mask ? ratio : 0.0f;                      // match_dists (8192,1)
    out[NB + 2 * i] = mask ? (float)i : -1.0f;         // matches_idxs[:,0]
    out[NB + 2 * i + 1] = mask ? (float)idx : -1.0f;   // matches_idxs[:,1]
    out[3 * NB + i] = mask ? 1.0f : 0.0f;              // mask
}

extern "C" void kernel_launch(void* const* d_in, const int* in_sizes, int n_in,
                              void* d_out, int out_size, void* d_ws, size_t ws_size,
                              hipStream_t stream) {
    const float* desc1 = (const float*)d_in[0];
    const float* desc2 = (const float*)d_in[1];
    float* out = (float*)d_out;
    char* ws = (char*)d_ws;

    __bf16* d1b = (__bf16*)ws;                                   // 2 MB
    __bf16* d2b = (__bf16*)(ws + (size_t)2 * 1024 * 1024);       // 2 MB
    float* n1   = (float*)(ws + (size_t)4 * 1024 * 1024);        // 32 KB
    float* n2pc = (float*)(ws + (size_t)4 * 1024 * 1024 + 32768);// 32 KB
    unsigned* pmin1 = (unsigned*)(ws + (size_t)4 * 1024 * 1024 + 65536); // 512 KB
    unsigned* pmin2 = pmin1 + (size_t)NCHUNK * NB;                        // 512 KB

    conv_norm_kernel<<<2 * NB / 4, 256, 0, stream>>>(desc1, desc2, d1b, d2b, n1, n2pc);
    snn_main_kernel<<<dim3(NB / BM, NCHUNK), 256, 0, stream>>>(d1b, d2b, n2pc, pmin1, pmin2);
    snn_reduce_kernel<<<NB / 256, 256, 0, stream>>>(pmin1, pmin2, n1, out);
}